// Round 2
// baseline (912.417 us; speedup 1.0000x reference)
//
#include <hip/hip_runtime.h>
#include <math.h>

// Problem constants
#define NH     8
#define HD     64
#define NTOK   1024    // H*W = 32*32
#define CIN    256
#define HIDDEN 512     // NH*HD
#define O3     1536    // 3*HIDDEN
#define BATCH  8
#define ATT_SCALE 0.125f  // 1/sqrt(64)

// ---------------------------------------------------------------------------
// Generic tiled GEMM: C[b][m][p] = sum_k A[m][k] * B[b][k][p] (+ bias[m])
// (unchanged from round 1 — ~117 us combined, VALU-bound fp32)
// ---------------------------------------------------------------------------
template <int M, int K, bool HAS_BIAS>
__global__ __launch_bounds__(256, 2)
void gemm_kernel(const float* __restrict__ A, const float* __restrict__ Bm,
                 const float* __restrict__ bias, float* __restrict__ C)
{
    __shared__ float As[64][68];
    __shared__ float Bs[64][68];
    const int tj = threadIdx.x & 15;
    const int ti = threadIdx.x >> 4;
    const int p0 = blockIdx.x * 64;
    const int m0 = blockIdx.y * 64;
    const int b  = blockIdx.z;

    const float* Bb = Bm + (size_t)b * K * NTOK;
    float*       Cb = C  + (size_t)b * M * NTOK;

    float acc[4][4] = {};

    for (int kc = 0; kc < K; kc += 64) {
        __syncthreads();
        #pragma unroll
        for (int ii = 0; ii < 4; ++ii) {
            const int r = ti + 16 * ii;
            *(float4*)&As[r][4 * tj] =
                *(const float4*)&A[(size_t)(m0 + r) * K + kc + 4 * tj];
            *(float4*)&Bs[r][4 * tj] =
                *(const float4*)&Bb[(size_t)(kc + r) * NTOK + p0 + 4 * tj];
        }
        __syncthreads();

        #pragma unroll
        for (int k = 0; k < 64; ++k) {
            const float4 b4 = *(const float4*)&Bs[k][4 * tj];
            float av[4];
            #pragma unroll
            for (int r = 0; r < 4; ++r) av[r] = As[4 * ti + r][k];
            const float bv[4] = {b4.x, b4.y, b4.z, b4.w};
            #pragma unroll
            for (int r = 0; r < 4; ++r)
                #pragma unroll
                for (int c = 0; c < 4; ++c)
                    acc[r][c] += av[r] * bv[c];
        }
    }

    #pragma unroll
    for (int r = 0; r < 4; ++r) {
        const int m = m0 + 4 * ti + r;
        float bv = 0.0f;
        if (HAS_BIAS) bv = bias[m];
        float4 o;
        o.x = acc[r][0] + bv; o.y = acc[r][1] + bv;
        o.z = acc[r][2] + bv; o.w = acc[r][3] + bv;
        *(float4*)&Cb[(size_t)m * NTOK + p0 + 4 * tj] = o;
    }
}

// ---------------------------------------------------------------------------
// Flash attention v2 (fp32): j-tile 32, 44 KB LDS -> 3 blocks/CU,
// XCD-swizzled grid for K/V L2 residency, register-prefetch of next K/V tile.
// ---------------------------------------------------------------------------
#define JT 32

__global__ __launch_bounds__(256, 3)
void attn_kernel(const float* __restrict__ qkv, float* __restrict__ attn_out)
{
    __shared__ float Qs[64][68];   // Qs[d][i] (pre-scaled); reused for O^T at end
    __shared__ float Ks[64][36];   // Ks[d][j]   stride 36 words: b128 rows aligned
    __shared__ float Vs[64][36];   // Vs[d][j]
    __shared__ float Ps[64][36];   // Ps[i][j]

    const int t  = threadIdx.x;
    const int tj = t & 15;
    const int ti = t >> 4;         // 0..15

    // Bijective XCD swizzle: all 16 i-tile blocks of a (b,h) land on one XCD.
    const int bid     = blockIdx.x;            // 0..1023
    const int logical = (bid & 7) * 128 + (bid >> 3);
    const int it = logical & 15;
    const int h  = (logical >> 4) & 7;
    const int b  = logical >> 7;
    const int i0 = it * 64;

    const float* Qg = qkv + ((size_t)b * O3 + 0 * HIDDEN + h * HD) * NTOK;
    const float* Kg = qkv + ((size_t)b * O3 + 1 * HIDDEN + h * HD) * NTOK;
    const float* Vg = qkv + ((size_t)b * O3 + 2 * HIDDEN + h * HD) * NTOK;

    // Q tile -> LDS, pre-scaled.
    #pragma unroll
    for (int ii = 0; ii < 4; ++ii) {
        const int d = ti + 16 * ii;
        float4 q = *(const float4*)&Qg[(size_t)d * NTOK + i0 + 4 * tj];
        q.x *= ATT_SCALE; q.y *= ATT_SCALE; q.z *= ATT_SCALE; q.w *= ATT_SCALE;
        *(float4*)&Qs[d][4 * tj] = q;
    }

    // K/V staging map: thread covers rows d0=t>>3 and d0+32, cols c..c+3.
    const int dr = t >> 3;         // 0..31
    const int c  = (t & 7) * 4;    // 0,4,...,28

    // Prefetch tile jt=0 into registers.
    float4 kcur0 = *(const float4*)&Kg[(size_t)dr * NTOK + c];
    float4 kcur1 = *(const float4*)&Kg[(size_t)(dr + 32) * NTOK + c];
    float4 vcur0 = *(const float4*)&Vg[(size_t)dr * NTOK + c];
    float4 vcur1 = *(const float4*)&Vg[(size_t)(dr + 32) * NTOK + c];

    float m_run[4], l_run[4], o_acc[4][4];
    #pragma unroll
    for (int r = 0; r < 4; ++r) {
        m_run[r] = -INFINITY; l_run[r] = 0.0f;
        #pragma unroll
        for (int cc = 0; cc < 4; ++cc) o_acc[r][cc] = 0.0f;
    }

    for (int jt = 0; jt < NTOK / JT; ++jt) {
        __syncthreads();   // previous PV done reading Ks/Vs
        *(float4*)&Ks[dr][c]      = kcur0;
        *(float4*)&Ks[dr + 32][c] = kcur1;
        *(float4*)&Vs[dr][c]      = vcur0;
        *(float4*)&Vs[dr + 32][c] = vcur1;

        // Issue next tile's loads (wrap on last iter; data unused, L2-hot).
        const int jn = ((jt + 1) & (NTOK / JT - 1)) * JT;
        float4 knxt0 = *(const float4*)&Kg[(size_t)dr * NTOK + jn + c];
        float4 knxt1 = *(const float4*)&Kg[(size_t)(dr + 32) * NTOK + jn + c];
        float4 vnxt0 = *(const float4*)&Vg[(size_t)dr * NTOK + jn + c];
        float4 vnxt1 = *(const float4*)&Vg[(size_t)(dr + 32) * NTOK + jn + c];

        __syncthreads();   // Ks/Vs ready

        // ---- S tile: rows i=4ti+r, cols j=2tj+{0,1} ----
        float s[4][2] = {};
        #pragma unroll
        for (int d = 0; d < 64; ++d) {
            const float4 q4 = *(const float4*)&Qs[d][4 * ti];       // 4-addr broadcast
            const float2 k2 = *(const float2*)&Ks[d][2 * tj];       // conflict-free
            const float qa[4] = {q4.x, q4.y, q4.z, q4.w};
            #pragma unroll
            for (int r = 0; r < 4; ++r) {
                s[r][0] += qa[r] * k2.x;
                s[r][1] += qa[r] * k2.y;
            }
        }

        // ---- online softmax ----
        #pragma unroll
        for (int r = 0; r < 4; ++r) {
            float mt = fmaxf(s[r][0], s[r][1]);
            #pragma unroll
            for (int off = 1; off < 16; off <<= 1)
                mt = fmaxf(mt, __shfl_xor(mt, off));
            const float m_new = fmaxf(m_run[r], mt);
            const float corr  = __expf(m_run[r] - m_new);
            const float p0 = __expf(s[r][0] - m_new);
            const float p1 = __expf(s[r][1] - m_new);
            float lt = p0 + p1;
            #pragma unroll
            for (int off = 1; off < 16; off <<= 1)
                lt += __shfl_xor(lt, off);
            l_run[r] = l_run[r] * corr + lt;
            m_run[r] = m_new;
            #pragma unroll
            for (int cc = 0; cc < 4; ++cc) o_acc[r][cc] *= corr;
            *(float2*)&Ps[4 * ti + r][2 * tj] = make_float2(p0, p1);
        }
        __syncthreads();   // Ps ready

        // ---- PV: o_acc[r][rr] = O[i=4ti+r][d=tj+16rr] ----
        #pragma unroll
        for (int j = 0; j < JT; j += 4) {
            float4 vv[4];
            #pragma unroll
            for (int rr = 0; rr < 4; ++rr)
                vv[rr] = *(const float4*)&Vs[tj + 16 * rr][j];
            #pragma unroll
            for (int r = 0; r < 4; ++r) {
                const float4 p4 = *(const float4*)&Ps[4 * ti + r][j];
                #pragma unroll
                for (int rr = 0; rr < 4; ++rr)
                    o_acc[r][rr] += p4.x * vv[rr].x + p4.y * vv[rr].y +
                                    p4.z * vv[rr].z + p4.w * vv[rr].w;
            }
        }

        kcur0 = knxt0; kcur1 = knxt1; vcur0 = vnxt0; vcur1 = vnxt1;
    }

    // ---- normalize; transpose O via Qs (free now); coalesced store ----
    __syncthreads();
    #pragma unroll
    for (int r = 0; r < 4; ++r) {
        const float inv = 1.0f / l_run[r];
        #pragma unroll
        for (int rr = 0; rr < 4; ++rr)
            Qs[tj + 16 * rr][4 * ti + r] = o_acc[r][rr] * inv;   // O^T[d][i]
    }
    __syncthreads();
    float* Og = attn_out + ((size_t)b * HIDDEN + h * HD) * NTOK;
    #pragma unroll
    for (int ii = 0; ii < 4; ++ii) {
        const int d = ti + 16 * ii;
        *(float4*)&Og[(size_t)d * NTOK + i0 + 4 * tj] = *(const float4*)&Qs[d][4 * tj];
    }
}

// ---------------------------------------------------------------------------
extern "C" void kernel_launch(void* const* d_in, const int* in_sizes, int n_in,
                              void* d_out, int out_size, void* d_ws, size_t ws_size,
                              hipStream_t stream)
{
    const float* x    = (const float*)d_in[0];   // [8][256][1024]
    const float* Wqkv = (const float*)d_in[1];   // [1536][256]
    const float* Wout = (const float*)d_in[2];   // [256][512]
    const float* bout = (const float*)d_in[3];   // [256]
    float* out = (float*)d_out;                  // [8][256][1024]

    float* qkv  = (float*)d_ws;                          // 48 MiB
    float* attn = qkv + (size_t)BATCH * O3 * NTOK;       // 16 MiB

    gemm_kernel<O3, CIN, false>
        <<<dim3(NTOK / 64, O3 / 64, BATCH), 256, 0, stream>>>(Wqkv, x, nullptr, qkv);

    attn_kernel<<<dim3(1024), 256, 0, stream>>>(qkv, attn);

    gemm_kernel<CIN, HIDDEN, true>
        <<<dim3(NTOK / 64, CIN / 64, BATCH), 256, 0, stream>>>(Wout, attn, bout, out);
}

// Round 4
// 255.913 us; speedup vs baseline: 3.5653x; 3.5653x over previous
//
#include <hip/hip_runtime.h>
#include <math.h>

#define NH 8
#define HD 64
#define NTOK 1024
#define CIN 256
#define HIDDEN 512
#define O3 1536
#define BATCH 8
#define ATT_SCALE 0.125f

typedef unsigned short u16;
typedef __attribute__((ext_vector_type(8))) short s16x8;   // 8 bf16 (4 VGPRs)
typedef __attribute__((ext_vector_type(4))) float f32x4;   // MFMA C/D
typedef __attribute__((ext_vector_type(4))) unsigned short u16x4;

__device__ __forceinline__ u16 f2bf(float f) {             // RNE fp32->bf16
    union { float f; unsigned int u; } v; v.f = f;
    v.u += 0x7fff + ((v.u >> 16) & 1);
    return (u16)(v.u >> 16);
}

// LDS tiles are [64 rows][64 bf16] (128 B rows), XOR-swizzled: byte ^= (row&7)<<4.
__device__ __forceinline__ s16x8 ld_frag(const u16* buf, int row, int chunk) {
    const int byte = (row * 128 + chunk * 16) ^ ((row & 7) << 4);
    return *(const s16x8*)((const char*)buf + byte);
}
__device__ __forceinline__ void st_stage(u16* buf, int t, s16x8 v0, s16x8 v1) {
    const int row = t >> 2, ch = t & 3;
    *(s16x8*)((char*)buf + ((row * 128 + ch * 16)       ^ ((row & 7) << 4))) = v0;
    *(s16x8*)((char*)buf + ((row * 128 + (ch + 4) * 16) ^ ((row & 7) << 4))) = v1;
}

// ---------------------------------------------------------------------------
// QKV projection (fp32 math). Epilogue emits bf16:
//   Q,K -> qkt[b][s][h][token][d]  (token-major, Q pre-scaled by 1/8)
//   V   -> vd [b][h][d][token]     (d-major)
// ---------------------------------------------------------------------------
__global__ __launch_bounds__(256, 2)
void gemm_qkv(const float* __restrict__ A, const float* __restrict__ Bm,
              u16* __restrict__ qkt, u16* __restrict__ vdst)
{
    __shared__ float As[64][68];
    __shared__ float Bs[64][68];
    const int tj = threadIdx.x & 15;
    const int ti = threadIdx.x >> 4;
    const int p0 = blockIdx.x * 64;
    const int m0 = blockIdx.y * 64;
    const int b  = blockIdx.z;
    const float* Bb = Bm + (size_t)b * CIN * NTOK;

    float acc[4][4] = {};
    for (int kc = 0; kc < CIN; kc += 64) {
        __syncthreads();
        #pragma unroll
        for (int ii = 0; ii < 4; ++ii) {
            const int r = ti + 16 * ii;
            *(float4*)&As[r][4 * tj] =
                *(const float4*)&A[(size_t)(m0 + r) * CIN + kc + 4 * tj];
            *(float4*)&Bs[r][4 * tj] =
                *(const float4*)&Bb[(size_t)(kc + r) * NTOK + p0 + 4 * tj];
        }
        __syncthreads();
        #pragma unroll
        for (int k = 0; k < 64; ++k) {
            const float4 b4 = *(const float4*)&Bs[k][4 * tj];
            float av[4];
            #pragma unroll
            for (int r = 0; r < 4; ++r) av[r] = As[4 * ti + r][k];
            const float bv[4] = {b4.x, b4.y, b4.z, b4.w};
            #pragma unroll
            for (int r = 0; r < 4; ++r)
                #pragma unroll
                for (int c = 0; c < 4; ++c)
                    acc[r][c] += av[r] * bv[c];
        }
    }

    if (m0 < 1024) {
        // Q or K: transpose to [token][d] bf16 via LDS bounce (stride 72: 16B-aligned rows)
        const float scale = (m0 < 512) ? ATT_SCALE : 1.0f;
        u16* T = (u16*)&As[0][0];
        __syncthreads();
        #pragma unroll
        for (int r = 0; r < 4; ++r)
            #pragma unroll
            for (int c = 0; c < 4; ++c)
                T[(4 * tj + c) * 72 + 4 * ti + r] = f2bf(acc[r][c] * scale);
        __syncthreads();
        const int sidx = (m0 < 512) ? 0 : 1;
        const int h = (m0 & 511) >> 6;
        u16* dst = qkt + ((((size_t)b * 2 + sidx) * NH + h) * NTOK + p0) * 64;
        const int row = threadIdx.x >> 2, ch = threadIdx.x & 3;
        *(s16x8*)(dst + row * 64 + ch * 8)      = *(const s16x8*)(T + row * 72 + ch * 8);
        *(s16x8*)(dst + row * 64 + ch * 8 + 32) = *(const s16x8*)(T + row * 72 + ch * 8 + 32);
    } else {
        // V: keep d-major, convert to bf16
        const int h = (m0 - 1024) >> 6;
        u16* dst = vdst + (((size_t)b * NH + h) * 64) * NTOK + p0;
        #pragma unroll
        for (int r = 0; r < 4; ++r) {
            u16x4 pv = { f2bf(acc[r][0]), f2bf(acc[r][1]), f2bf(acc[r][2]), f2bf(acc[r][3]) };
            *(u16x4*)(dst + (size_t)(4 * ti + r) * NTOK + 4 * tj) = pv;
        }
    }
}

// ---------------------------------------------------------------------------
// Flash attention, bf16 MFMA. Block = 256 thr = 4 waves; wave w owns 16 q-rows.
// S = mfma(A=Q[i][d], B=K[j][d]); D: col j=lane&15, row i=(lane>>4)*4+r.
// O^T = mfma(A=V[d][j], B=P[i][j]); D: col i=lane&15, row d=(lane>>4)*4+r.
// ---------------------------------------------------------------------------
__global__ __launch_bounds__(256, 4)
void attn_kernel(const u16* __restrict__ qkt, const u16* __restrict__ vd,
                 float* __restrict__ attn_out)
{
    __shared__ u16 Qt[64 * 64];   // [i][d] swz
    __shared__ u16 Kt[64 * 64];   // [j][d] swz
    __shared__ u16 Vt[64 * 64];   // [d][j] swz
    __shared__ u16 Ps[64 * 64];   // [i][j] swz
    __shared__ float red[64];     // per-row corr / 1/l broadcast

    const int t    = threadIdx.x;
    const int lane = t & 63;
    const int w    = t >> 6;      // wave 0..3
    const int lr   = lane & 15;
    const int lq   = lane >> 4;   // 0..3

    // Bijective XCD swizzle: XCD x gets batch b=x; K+V bf16 = 2 MB -> L2-resident.
    const int bid     = blockIdx.x;
    const int logical = (bid & 7) * 128 + (bid >> 3);
    const int it = logical & 15;
    const int h  = (logical >> 4) & 7;
    const int b  = logical >> 7;
    const int i0 = it * 64;

    const int srow = t >> 2, sch = t & 3;   // staging map: row, 2x16B chunks
    const u16* qg = qkt + ((((size_t)b * 2 + 0) * NH + h) * NTOK + i0 + srow) * 64 + sch * 8;
    const u16* kg = qkt + ((((size_t)b * 2 + 1) * NH + h) * NTOK + srow) * 64 + sch * 8;
    const u16* vg = vd  + (((size_t)b * NH + h) * 64 + srow) * NTOK + sch * 8;

    st_stage(Qt, t, *(const s16x8*)qg, *(const s16x8*)(qg + 32));

    s16x8 k0 = *(const s16x8*)kg, k1 = *(const s16x8*)(kg + 32);
    s16x8 v0 = *(const s16x8*)vg, v1 = *(const s16x8*)(vg + 32);

    f32x4 o0 = {0.f,0.f,0.f,0.f}, o1 = o0, o2 = o0, o3 = o0;
    float m_run[4] = {-INFINITY, -INFINITY, -INFINITY, -INFINITY};
    float l_run[4] = {0.f, 0.f, 0.f, 0.f};

    for (int jt = 0; jt < 16; ++jt) {
        __syncthreads();                       // prior tile's LDS reads done
        st_stage(Kt, t, k0, k1);
        st_stage(Vt, t, v0, v1);
        const int jn = (jt + 1) & 15;          // prefetch next tile (wraps; L2-hot)
        k0 = *(const s16x8*)(kg + (size_t)jn * 4096);
        k1 = *(const s16x8*)(kg + (size_t)jn * 4096 + 32);
        v0 = *(const s16x8*)(vg + (size_t)jn * 64);
        v1 = *(const s16x8*)(vg + (size_t)jn * 64 + 32);
        __syncthreads();                       // K/V tiles ready

        // ---- QK^T: S[16 i][64 j] per wave = 4 n-subtiles x 2 k-steps ----
        f32x4 s0 = {0.f,0.f,0.f,0.f}, s1 = s0, s2 = s0, s3 = s0;
        #pragma unroll
        for (int ks = 0; ks < 2; ++ks) {
            const s16x8 qa = ld_frag(Qt, w * 16 + lr, ks * 4 + lq);
            s0 = __builtin_amdgcn_mfma_f32_16x16x32_bf16(qa, ld_frag(Kt,      lr, ks*4+lq), s0, 0,0,0);
            s1 = __builtin_amdgcn_mfma_f32_16x16x32_bf16(qa, ld_frag(Kt, 16 + lr, ks*4+lq), s1, 0,0,0);
            s2 = __builtin_amdgcn_mfma_f32_16x16x32_bf16(qa, ld_frag(Kt, 32 + lr, ks*4+lq), s2, 0,0,0);
            s3 = __builtin_amdgcn_mfma_f32_16x16x32_bf16(qa, ld_frag(Kt, 48 + lr, ks*4+lq), s3, 0,0,0);
        }

        // ---- online softmax; lane holds rows i=w*16+lq*4+r, cols j=lr+16*js ----
        #pragma unroll
        for (int r = 0; r < 4; ++r) {
            float sm = fmaxf(fmaxf(s0[r], s1[r]), fmaxf(s2[r], s3[r]));
            sm = fmaxf(sm, __shfl_xor(sm, 1));
            sm = fmaxf(sm, __shfl_xor(sm, 2));
            sm = fmaxf(sm, __shfl_xor(sm, 4));
            sm = fmaxf(sm, __shfl_xor(sm, 8));
            const float mnew = fmaxf(m_run[r], sm);
            const float corr = __expf(m_run[r] - mnew);
            const float p0 = __expf(s0[r] - mnew);
            const float p1 = __expf(s1[r] - mnew);
            const float p2 = __expf(s2[r] - mnew);
            const float p3 = __expf(s3[r] - mnew);
            float lt = (p0 + p1) + (p2 + p3);
            lt += __shfl_xor(lt, 1);
            lt += __shfl_xor(lt, 2);
            lt += __shfl_xor(lt, 4);
            lt += __shfl_xor(lt, 8);
            l_run[r] = l_run[r] * corr + lt;
            m_run[r] = mnew;
            if (lr == 0) red[w * 16 + lq * 4 + r] = corr;
            const int i = w * 16 + lq * 4 + r;
            char* pr = (char*)Ps;
            *(u16*)(pr + ((i * 128 + (lr     ) * 2) ^ ((i & 7) << 4))) = f2bf(p0);
            *(u16*)(pr + ((i * 128 + (lr + 16) * 2) ^ ((i & 7) << 4))) = f2bf(p1);
            *(u16*)(pr + ((i * 128 + (lr + 32) * 2) ^ ((i & 7) << 4))) = f2bf(p2);
            *(u16*)(pr + ((i * 128 + (lr + 48) * 2) ^ ((i & 7) << 4))) = f2bf(p3);
        }

        // rescale O accumulator (o-layout lane's query i = lane&15 via LDS bcast)
        const float ci = red[w * 16 + lr];
        o0 *= ci; o1 *= ci; o2 *= ci; o3 *= ci;

        // ---- PV: O^T[64 d][16 i] per wave = 4 m-subtiles x 2 k-steps ----
        #pragma unroll
        for (int ks = 0; ks < 2; ++ks) {
            const s16x8 pb = ld_frag(Ps, w * 16 + lr, ks * 4 + lq);
            o0 = __builtin_amdgcn_mfma_f32_16x16x32_bf16(ld_frag(Vt,      lr, ks*4+lq), pb, o0, 0,0,0);
            o1 = __builtin_amdgcn_mfma_f32_16x16x32_bf16(ld_frag(Vt, 16 + lr, ks*4+lq), pb, o1, 0,0,0);
            o2 = __builtin_amdgcn_mfma_f32_16x16x32_bf16(ld_frag(Vt, 32 + lr, ks*4+lq), pb, o2, 0,0,0);
            o3 = __builtin_amdgcn_mfma_f32_16x16x32_bf16(ld_frag(Vt, 48 + lr, ks*4+lq), pb, o3, 0,0,0);
        }
    }

    // ---- normalize (1/l via LDS bcast) and store O^T[d][i] fp32 ----
    #pragma unroll
    for (int r = 0; r < 4; ++r)
        if (lr == 0) red[w * 16 + lq * 4 + r] = 1.0f / l_run[r];
    const float inv = red[w * 16 + lr];
    float* og = attn_out + (((size_t)b * NH + h) * 64) * NTOK + i0 + w * 16 + lr;
    #pragma unroll
    for (int r = 0; r < 4; ++r) {
        og[(size_t)( 0 + lq * 4 + r) * NTOK] = o0[r] * inv;
        og[(size_t)(16 + lq * 4 + r) * NTOK] = o1[r] * inv;
        og[(size_t)(32 + lq * 4 + r) * NTOK] = o2[r] * inv;
        og[(size_t)(48 + lq * 4 + r) * NTOK] = o3[r] * inv;
    }
}

// ---------------------------------------------------------------------------
// Output projection (fp32): out[b][c][p] = sum_o Wout[c][o]*attn[b][o][p] + bout[c]
// ---------------------------------------------------------------------------
__global__ __launch_bounds__(256, 2)
void gemm_out(const float* __restrict__ A, const float* __restrict__ Bm,
              const float* __restrict__ bias, float* __restrict__ C)
{
    __shared__ float As[64][68];
    __shared__ float Bs[64][68];
    const int tj = threadIdx.x & 15;
    const int ti = threadIdx.x >> 4;
    const int p0 = blockIdx.x * 64;
    const int m0 = blockIdx.y * 64;
    const int b  = blockIdx.z;
    const float* Bb = Bm + (size_t)b * HIDDEN * NTOK;
    float*       Cb = C  + (size_t)b * CIN * NTOK;

    float acc[4][4] = {};
    for (int kc = 0; kc < HIDDEN; kc += 64) {
        __syncthreads();
        #pragma unroll
        for (int ii = 0; ii < 4; ++ii) {
            const int r = ti + 16 * ii;
            *(float4*)&As[r][4 * tj] =
                *(const float4*)&A[(size_t)(m0 + r) * HIDDEN + kc + 4 * tj];
            *(float4*)&Bs[r][4 * tj] =
                *(const float4*)&Bb[(size_t)(kc + r) * NTOK + p0 + 4 * tj];
        }
        __syncthreads();
        #pragma unroll
        for (int k = 0; k < 64; ++k) {
            const float4 b4 = *(const float4*)&Bs[k][4 * tj];
            float av[4];
            #pragma unroll
            for (int r = 0; r < 4; ++r) av[r] = As[4 * ti + r][k];
            const float bv[4] = {b4.x, b4.y, b4.z, b4.w};
            #pragma unroll
            for (int r = 0; r < 4; ++r)
                #pragma unroll
                for (int c = 0; c < 4; ++c)
                    acc[r][c] += av[r] * bv[c];
        }
    }
    #pragma unroll
    for (int r = 0; r < 4; ++r) {
        const int m = m0 + 4 * ti + r;
        const float bv = bias[m];
        float4 o;
        o.x = acc[r][0] + bv; o.y = acc[r][1] + bv;
        o.z = acc[r][2] + bv; o.w = acc[r][3] + bv;
        *(float4*)&Cb[(size_t)m * NTOK + p0 + 4 * tj] = o;
    }
}

// ---------------------------------------------------------------------------
extern "C" void kernel_launch(void* const* d_in, const int* in_sizes, int n_in,
                              void* d_out, int out_size, void* d_ws, size_t ws_size,
                              hipStream_t stream)
{
    const float* x    = (const float*)d_in[0];   // [8][256][1024]
    const float* Wqkv = (const float*)d_in[1];   // [1536][256]
    const float* Wout = (const float*)d_in[2];   // [256][512]
    const float* bout = (const float*)d_in[3];   // [256]
    float* out = (float*)d_out;                  // [8][256][1024]

    u16*   qkt  = (u16*)d_ws;                                    // 16 MiB bf16 Q,K [b][s][h][tok][d]
    u16*   vbuf = qkt + (size_t)BATCH * 2 * NH * NTOK * 64;      //  8 MiB bf16 V [b][h][d][tok]
    float* attn = (float*)(vbuf + (size_t)BATCH * NH * 64 * NTOK); // 16 MiB fp32 [b][o][tok]

    gemm_qkv<<<dim3(NTOK / 64, O3 / 64, BATCH), 256, 0, stream>>>(Wqkv, x, qkt, vbuf);
    attn_kernel<<<dim3(1024), 256, 0, stream>>>(qkt, vbuf, attn);
    gemm_out<<<dim3(NTOK / 64, CIN / 64, BATCH), 256, 0, stream>>>(Wout, attn, bout, out);
}

// Round 6
// 184.512 us; speedup vs baseline: 4.9450x; 1.3870x over previous
//
#include <hip/hip_runtime.h>
#include <math.h>

#define NH 8
#define HD 64
#define NTOK 1024
#define CIN 256
#define HIDDEN 512
#define O3 1536
#define BATCH 8
#define ATT_SCALE 0.125f

typedef unsigned short u16;
typedef __attribute__((ext_vector_type(8))) short s16x8;   // 8 bf16 (4 VGPRs)
typedef __attribute__((ext_vector_type(4))) float f32x4;   // MFMA C/D
typedef __attribute__((ext_vector_type(4))) unsigned short u16x4;

__device__ __forceinline__ u16 f2bf(float f) {             // RNE fp32->bf16
    union { float f; unsigned int u; } v; v.f = f;
    v.u += 0x7fff + ((v.u >> 16) & 1);
    return (u16)(v.u >> 16);
}
__device__ __forceinline__ float bf2f(u16 h) {
    union { unsigned int u; float f; } v; v.u = (unsigned)h << 16;
    return v.f;
}
__device__ __forceinline__ void split2(float x, u16& hi, u16& lo) {
    const u16 h = f2bf(x);
    hi = h;
    lo = f2bf(x - bf2f(h));                                // residual ~2^-17 relative
}

// Swizzled LDS tile [64 rows][64 bf16] (128 B rows): byte ^= (row&7)<<4.
__device__ __forceinline__ s16x8 ldf(const u16* buf, int row, int chunk) {
    const int byte = (row * 128 + chunk * 16) ^ ((row & 7) << 4);
    return *(const s16x8*)((const char*)buf + byte);
}
__device__ __forceinline__ void st32(u16* buf, int row, int ch, s16x8 a, s16x8 b) {
    char* p = (char*)buf;
    *(s16x8*)(p + ((row * 128 + ch * 32) ^ ((row & 7) << 4)))      = a;
    *(s16x8*)(p + ((row * 128 + ch * 32 + 16) ^ ((row & 7) << 4))) = b;
}
// attn staging variant (round-4 validated): chunks ch and ch+4
__device__ __forceinline__ void st_stage(u16* buf, int t, s16x8 v0, s16x8 v1) {
    const int row = t >> 2, ch = t & 3;
    *(s16x8*)((char*)buf + ((row * 128 + ch * 16)       ^ ((row & 7) << 4))) = v0;
    *(s16x8*)((char*)buf + ((row * 128 + (ch + 4) * 16) ^ ((row & 7) << 4))) = v1;
}

// ---------------------------------------------------------------------------
// Prep: split fp32 array into hi/lo bf16
// ---------------------------------------------------------------------------
__global__ __launch_bounds__(256)
void split_f32(const float* __restrict__ src, u16* __restrict__ hi,
               u16* __restrict__ lo, int n4)
{
    const int i = blockIdx.x * 256 + threadIdx.x;
    if (i >= n4) return;
    const float4 v = ((const float4*)src)[i];
    u16 h0,h1,h2,h3,l0,l1,l2,l3;
    split2(v.x,h0,l0); split2(v.y,h1,l1); split2(v.z,h2,l2); split2(v.w,h3,l3);
    u16x4 H = {h0,h1,h2,h3}, L = {l0,l1,l2,l3};
    ((u16x4*)hi)[i] = H;
    ((u16x4*)lo)[i] = L;
}

// ---------------------------------------------------------------------------
// Prep: transpose x [b][c][p] fp32 -> xT hi/lo [b][p][c] bf16 (64x64 tiles)
// ---------------------------------------------------------------------------
__global__ __launch_bounds__(256)
void xpose_x(const float* __restrict__ x, u16* __restrict__ xthi,
             u16* __restrict__ xtlo)
{
    __shared__ float T[64][68];
    const int t  = threadIdx.x;
    const int p0 = blockIdx.x * 64;
    const int c0 = blockIdx.y * 64;
    const int b  = blockIdx.z;
    const int cl = t >> 4, pj = (t & 15) * 4;
    #pragma unroll
    for (int k = 0; k < 4; ++k)
        *(float4*)&T[cl + 16 * k][pj] =
            *(const float4*)&x[((size_t)b * CIN + c0 + cl + 16 * k) * NTOK + p0 + pj];
    __syncthreads();
    const int p = t >> 2, ch = t & 3;
    u16* dhi = xthi + ((size_t)b * NTOK + p0 + p) * CIN + c0 + ch * 16;
    u16* dlo = xtlo + ((size_t)b * NTOK + p0 + p) * CIN + c0 + ch * 16;
    #pragma unroll
    for (int g = 0; g < 2; ++g) {
        s16x8 H, L;
        #pragma unroll
        for (int e = 0; e < 8; ++e) {
            u16 hh, ll;
            split2(T[ch * 16 + g * 8 + e][p], hh, ll);
            H[e] = (short)hh; L[e] = (short)ll;
        }
        *(s16x8*)(dhi + g * 8) = H;
        *(s16x8*)(dlo + g * 8) = L;
    }
}

// ---------------------------------------------------------------------------
// QKV projection, split-bf16 MFMA (3 products ~ fp32 accuracy).
// A = W[o][c] hi/lo; B = xT[p][c] hi/lo. D rows=o, cols=p.
// Epilogue: Q,K -> qkt[b][s][h][tok][64] (Q pre-scaled); V -> vd[b][h][64][tok].
// ---------------------------------------------------------------------------
__global__ __launch_bounds__(256, 4)
void gemm_qkv_mfma(const u16* __restrict__ Whi, const u16* __restrict__ Wlo,
                   const u16* __restrict__ Xhi, const u16* __restrict__ Xlo,
                   u16* __restrict__ qkt, u16* __restrict__ vd)
{
    __shared__ __align__(16) char smem[32768];
    u16* Ah = (u16*)smem;
    u16* Al = (u16*)(smem + 8192);
    u16* Bh = (u16*)(smem + 16384);
    u16* Bl = (u16*)(smem + 24576);

    const int t = threadIdx.x;
    const int lane = t & 63, w = t >> 6;
    const int lr = lane & 15, lq = lane >> 4;
    const int p0 = blockIdx.x * 64;
    const int m0 = blockIdx.y * 64;
    const int b  = blockIdx.z;
    const int row = t >> 2, ch = t & 3;

    const u16* wh = Whi + (size_t)(m0 + row) * CIN + ch * 16;
    const u16* wl = Wlo + (size_t)(m0 + row) * CIN + ch * 16;
    const u16* xh = Xhi + ((size_t)b * NTOK + p0 + row) * CIN + ch * 16;
    const u16* xl = Xlo + ((size_t)b * NTOK + p0 + row) * CIN + ch * 16;

    f32x4 acc[4] = {};
    for (int kc = 0; kc < CIN; kc += 64) {
        __syncthreads();
        st32(Ah, row, ch, *(const s16x8*)(wh + kc), *(const s16x8*)(wh + kc + 8));
        st32(Al, row, ch, *(const s16x8*)(wl + kc), *(const s16x8*)(wl + kc + 8));
        st32(Bh, row, ch, *(const s16x8*)(xh + kc), *(const s16x8*)(xh + kc + 8));
        st32(Bl, row, ch, *(const s16x8*)(xl + kc), *(const s16x8*)(xl + kc + 8));
        __syncthreads();
        #pragma unroll
        for (int ks = 0; ks < 2; ++ks) {
            const s16x8 ah = ldf(Ah, w * 16 + lr, ks * 4 + lq);
            const s16x8 al = ldf(Al, w * 16 + lr, ks * 4 + lq);
            #pragma unroll
            for (int js = 0; js < 4; ++js) {
                const s16x8 bh = ldf(Bh, js * 16 + lr, ks * 4 + lq);
                const s16x8 bl = ldf(Bl, js * 16 + lr, ks * 4 + lq);
                acc[js] = __builtin_amdgcn_mfma_f32_16x16x32_bf16(ah, bh, acc[js], 0, 0, 0);
                acc[js] = __builtin_amdgcn_mfma_f32_16x16x32_bf16(al, bh, acc[js], 0, 0, 0);
                acc[js] = __builtin_amdgcn_mfma_f32_16x16x32_bf16(ah, bl, acc[js], 0, 0, 0);
            }
        }
    }

    __syncthreads();
    u16* T = Ah;                          // 8 KB bounce tile
    char* Tc = (char*)T;
    if (m0 < 1024) {
        // Q or K: bounce transposed T[p][o], store [tok][d] coalesced
        const float scale = (m0 < 512) ? ATT_SCALE : 1.0f;
        #pragma unroll
        for (int js = 0; js < 4; ++js) {
            const int p = js * 16 + lr;
            #pragma unroll
            for (int r = 0; r < 4; ++r) {
                const int o = w * 16 + lq * 4 + r;
                *(u16*)(Tc + ((p * 128 + o * 2) ^ ((p & 7) << 4))) = f2bf(acc[js][r] * scale);
            }
        }
        __syncthreads();
        const int sidx = (m0 < 512) ? 0 : 1;
        const int h = (m0 & 511) >> 6;
        u16* dst = qkt + ((((size_t)b * 2 + sidx) * NH + h) * NTOK + p0 + row) * 64 + ch * 16;
        *(s16x8*)dst       = *(const s16x8*)(Tc + ((row * 128 + ch * 32)      ^ ((row & 7) << 4)));
        *(s16x8*)(dst + 8) = *(const s16x8*)(Tc + ((row * 128 + ch * 32 + 16) ^ ((row & 7) << 4)));
    } else {
        // V: bounce direct T[o][p], store [d][tok] coalesced
        const int h = (m0 - 1024) >> 6;
        #pragma unroll
        for (int js = 0; js < 4; ++js) {
            const int p = js * 16 + lr;
            #pragma unroll
            for (int r = 0; r < 4; ++r) {
                const int o = w * 16 + lq * 4 + r;
                *(u16*)(Tc + ((o * 128 + p * 2) ^ ((o & 7) << 4))) = f2bf(acc[js][r]);
            }
        }
        __syncthreads();
        u16* dst = vd + (((size_t)b * NH + h) * 64 + row) * NTOK + p0 + ch * 16;
        *(s16x8*)dst       = *(const s16x8*)(Tc + ((row * 128 + ch * 32)      ^ ((row & 7) << 4)));
        *(s16x8*)(dst + 8) = *(const s16x8*)(Tc + ((row * 128 + ch * 32 + 16) ^ ((row & 7) << 4)));
    }
}

// ---------------------------------------------------------------------------
// Flash attention, bf16 MFMA — round-4 validated version (fp32 output
// attn_out[b][h*64+d][tok]).
// ---------------------------------------------------------------------------
__global__ __launch_bounds__(256, 4)
void attn_kernel(const u16* __restrict__ qkt, const u16* __restrict__ vd,
                 float* __restrict__ attn_out)
{
    __shared__ u16 Qt[64 * 64];
    __shared__ u16 Kt[64 * 64];
    __shared__ u16 Vt[64 * 64];
    __shared__ u16 Ps[64 * 64];
    __shared__ float red[64];

    const int t    = threadIdx.x;
    const int lane = t & 63;
    const int w    = t >> 6;
    const int lr   = lane & 15;
    const int lq   = lane >> 4;

    const int bid     = blockIdx.x;
    const int logical = (bid & 7) * 128 + (bid >> 3);
    const int it = logical & 15;
    const int h  = (logical >> 4) & 7;
    const int b  = logical >> 7;
    const int i0 = it * 64;

    const int srow = t >> 2, sch = t & 3;
    const u16* qg = qkt + ((((size_t)b * 2 + 0) * NH + h) * NTOK + i0 + srow) * 64 + sch * 8;
    const u16* kg = qkt + ((((size_t)b * 2 + 1) * NH + h) * NTOK + srow) * 64 + sch * 8;
    const u16* vg = vd  + (((size_t)b * NH + h) * 64 + srow) * NTOK + sch * 8;

    st_stage(Qt, t, *(const s16x8*)qg, *(const s16x8*)(qg + 32));

    s16x8 k0 = *(const s16x8*)kg, k1 = *(const s16x8*)(kg + 32);
    s16x8 v0 = *(const s16x8*)vg, v1 = *(const s16x8*)(vg + 32);

    f32x4 o0 = {0.f,0.f,0.f,0.f}, o1 = o0, o2 = o0, o3 = o0;
    float m_run[4] = {-INFINITY, -INFINITY, -INFINITY, -INFINITY};
    float l_run[4] = {0.f, 0.f, 0.f, 0.f};

    for (int jt = 0; jt < 16; ++jt) {
        __syncthreads();
        st_stage(Kt, t, k0, k1);
        st_stage(Vt, t, v0, v1);
        const int jn = (jt + 1) & 15;
        k0 = *(const s16x8*)(kg + (size_t)jn * 4096);
        k1 = *(const s16x8*)(kg + (size_t)jn * 4096 + 32);
        v0 = *(const s16x8*)(vg + (size_t)jn * 64);
        v1 = *(const s16x8*)(vg + (size_t)jn * 64 + 32);
        __syncthreads();

        f32x4 s0 = {0.f,0.f,0.f,0.f}, s1 = s0, s2 = s0, s3 = s0;
        #pragma unroll
        for (int ks = 0; ks < 2; ++ks) {
            const s16x8 qa = ldf(Qt, w * 16 + lr, ks * 4 + lq);
            s0 = __builtin_amdgcn_mfma_f32_16x16x32_bf16(qa, ldf(Kt,      lr, ks*4+lq), s0, 0,0,0);
            s1 = __builtin_amdgcn_mfma_f32_16x16x32_bf16(qa, ldf(Kt, 16 + lr, ks*4+lq), s1, 0,0,0);
            s2 = __builtin_amdgcn_mfma_f32_16x16x32_bf16(qa, ldf(Kt, 32 + lr, ks*4+lq), s2, 0,0,0);
            s3 = __builtin_amdgcn_mfma_f32_16x16x32_bf16(qa, ldf(Kt, 48 + lr, ks*4+lq), s3, 0,0,0);
        }

        #pragma unroll
        for (int r = 0; r < 4; ++r) {
            float sm = fmaxf(fmaxf(s0[r], s1[r]), fmaxf(s2[r], s3[r]));
            sm = fmaxf(sm, __shfl_xor(sm, 1));
            sm = fmaxf(sm, __shfl_xor(sm, 2));
            sm = fmaxf(sm, __shfl_xor(sm, 4));
            sm = fmaxf(sm, __shfl_xor(sm, 8));
            const float mnew = fmaxf(m_run[r], sm);
            const float corr = __expf(m_run[r] - mnew);
            const float p0 = __expf(s0[r] - mnew);
            const float p1 = __expf(s1[r] - mnew);
            const float p2 = __expf(s2[r] - mnew);
            const float p3 = __expf(s3[r] - mnew);
            float lt = (p0 + p1) + (p2 + p3);
            lt += __shfl_xor(lt, 1);
            lt += __shfl_xor(lt, 2);
            lt += __shfl_xor(lt, 4);
            lt += __shfl_xor(lt, 8);
            l_run[r] = l_run[r] * corr + lt;
            m_run[r] = mnew;
            if (lr == 0) red[w * 16 + lq * 4 + r] = corr;
            const int i = w * 16 + lq * 4 + r;
            char* pr = (char*)Ps;
            *(u16*)(pr + ((i * 128 + (lr     ) * 2) ^ ((i & 7) << 4))) = f2bf(p0);
            *(u16*)(pr + ((i * 128 + (lr + 16) * 2) ^ ((i & 7) << 4))) = f2bf(p1);
            *(u16*)(pr + ((i * 128 + (lr + 32) * 2) ^ ((i & 7) << 4))) = f2bf(p2);
            *(u16*)(pr + ((i * 128 + (lr + 48) * 2) ^ ((i & 7) << 4))) = f2bf(p3);
        }

        const float ci = red[w * 16 + lr];
        o0 *= ci; o1 *= ci; o2 *= ci; o3 *= ci;

        #pragma unroll
        for (int ks = 0; ks < 2; ++ks) {
            const s16x8 pb = ldf(Ps, w * 16 + lr, ks * 4 + lq);
            o0 = __builtin_amdgcn_mfma_f32_16x16x32_bf16(ldf(Vt,      lr, ks*4+lq), pb, o0, 0,0,0);
            o1 = __builtin_amdgcn_mfma_f32_16x16x32_bf16(ldf(Vt, 16 + lr, ks*4+lq), pb, o1, 0,0,0);
            o2 = __builtin_amdgcn_mfma_f32_16x16x32_bf16(ldf(Vt, 32 + lr, ks*4+lq), pb, o2, 0,0,0);
            o3 = __builtin_amdgcn_mfma_f32_16x16x32_bf16(ldf(Vt, 48 + lr, ks*4+lq), pb, o3, 0,0,0);
        }
    }

    // ---- normalize (1/l via LDS bcast) and store O^T[d][i] fp32 (round 4) ----
    #pragma unroll
    for (int r = 0; r < 4; ++r)
        if (lr == 0) red[w * 16 + lq * 4 + r] = 1.0f / l_run[r];
    const float inv = red[w * 16 + lr];
    float* og = attn_out + (((size_t)b * NH + h) * 64) * NTOK + i0 + w * 16 + lr;
    #pragma unroll
    for (int r = 0; r < 4; ++r) {
        og[(size_t)( 0 + lq * 4 + r) * NTOK] = o0[r] * inv;
        og[(size_t)(16 + lq * 4 + r) * NTOK] = o1[r] * inv;
        og[(size_t)(32 + lq * 4 + r) * NTOK] = o2[r] * inv;
        og[(size_t)(48 + lq * 4 + r) * NTOK] = o3[r] * inv;
    }
}

// ---------------------------------------------------------------------------
// Output projection (fp32, round-4 validated):
// out[b][c][p] = sum_o Wout[c][o]*attn[b][o][p] + bout[c]
// ---------------------------------------------------------------------------
__global__ __launch_bounds__(256, 2)
void gemm_out(const float* __restrict__ A, const float* __restrict__ Bm,
              const float* __restrict__ bias, float* __restrict__ C)
{
    __shared__ float As[64][68];
    __shared__ float Bs[64][68];
    const int tj = threadIdx.x & 15;
    const int ti = threadIdx.x >> 4;
    const int p0 = blockIdx.x * 64;
    const int m0 = blockIdx.y * 64;
    const int b  = blockIdx.z;
    const float* Bb = Bm + (size_t)b * HIDDEN * NTOK;
    float*       Cb = C  + (size_t)b * CIN * NTOK;

    float acc[4][4] = {};
    for (int kc = 0; kc < HIDDEN; kc += 64) {
        __syncthreads();
        #pragma unroll
        for (int ii = 0; ii < 4; ++ii) {
            const int r = ti + 16 * ii;
            *(float4*)&As[r][4 * tj] =
                *(const float4*)&A[(size_t)(m0 + r) * HIDDEN + kc + 4 * tj];
            *(float4*)&Bs[r][4 * tj] =
                *(const float4*)&Bb[(size_t)(kc + r) * NTOK + p0 + 4 * tj];
        }
        __syncthreads();
        #pragma unroll
        for (int k = 0; k < 64; ++k) {
            const float4 b4 = *(const float4*)&Bs[k][4 * tj];
            float av[4];
            #pragma unroll
            for (int r = 0; r < 4; ++r) av[r] = As[4 * ti + r][k];
            const float bv[4] = {b4.x, b4.y, b4.z, b4.w};
            #pragma unroll
            for (int r = 0; r < 4; ++r)
                #pragma unroll
                for (int c = 0; c < 4; ++c)
                    acc[r][c] += av[r] * bv[c];
        }
    }
    #pragma unroll
    for (int r = 0; r < 4; ++r) {
        const int m = m0 + 4 * ti + r;
        const float bv = bias[m];
        float4 o;
        o.x = acc[r][0] + bv; o.y = acc[r][1] + bv;
        o.z = acc[r][2] + bv; o.w = acc[r][3] + bv;
        *(float4*)&Cb[(size_t)m * NTOK + p0 + 4 * tj] = o;
    }
}

// ---------------------------------------------------------------------------
extern "C" void kernel_launch(void* const* d_in, const int* in_sizes, int n_in,
                              void* d_out, int out_size, void* d_ws, size_t ws_size,
                              hipStream_t stream)
{
    const float* x    = (const float*)d_in[0];   // [8][256][1024]
    const float* Wqkv = (const float*)d_in[1];   // [1536][256]
    const float* Wout = (const float*)d_in[2];   // [256][512]
    const float* bout = (const float*)d_in[3];   // [256]
    float* out = (float*)d_out;                  // [8][256][1024]

    char* ws = (char*)d_ws;
    u16* Wqhi = (u16*)ws;                         ws += (size_t)O3 * CIN * 2;        // 768 KB
    u16* Wqlo = (u16*)ws;                         ws += (size_t)O3 * CIN * 2;
    u16* xThi = (u16*)ws;                         ws += (size_t)BATCH * NTOK * CIN * 2;  // 4 MB
    u16* xTlo = (u16*)ws;                         ws += (size_t)BATCH * NTOK * CIN * 2;
    u16* qkt  = (u16*)ws;                         ws += (size_t)BATCH * 2 * NH * NTOK * HD * 2; // 16 MB
    u16* vd   = (u16*)ws;                         ws += (size_t)BATCH * NH * HD * NTOK * 2;     // 8 MB
    float* attn = (float*)ws;                     ws += (size_t)BATCH * HIDDEN * NTOK * 4;      // 16 MB

    split_f32<<<dim3(O3 * CIN / 1024), 256, 0, stream>>>(Wqkv, Wqhi, Wqlo, O3 * CIN / 4);
    xpose_x<<<dim3(16, 4, BATCH), 256, 0, stream>>>(x, xThi, xTlo);

    gemm_qkv_mfma<<<dim3(16, 24, BATCH), 256, 0, stream>>>(Wqhi, Wqlo, xThi, xTlo, qkt, vd);
    attn_kernel<<<dim3(1024), 256, 0, stream>>>(qkt, vd, attn);
    gemm_out<<<dim3(16, 4, BATCH), 256, 0, stream>>>(Wout, attn, bout, out);
}

// Round 9
// 144.557 us; speedup vs baseline: 6.3118x; 1.2764x over previous
//
#include <hip/hip_runtime.h>
#include <math.h>

#define NH 8
#define HD 64
#define NTOK 1024
#define CIN 256
#define HIDDEN 512
#define O3 1536
#define BATCH 8
#define ATT_SCALE 0.125f

typedef unsigned short u16;
typedef __attribute__((ext_vector_type(8))) short s16x8;   // 8 bf16 (4 VGPRs)
typedef __attribute__((ext_vector_type(4))) float f32x4;   // MFMA C/D
typedef __attribute__((ext_vector_type(4))) unsigned short u16x4;

__device__ __forceinline__ u16 f2bf(float f) {             // RNE fp32->bf16
    union { float f; unsigned int u; } v; v.f = f;
    v.u += 0x7fff + ((v.u >> 16) & 1);
    return (u16)(v.u >> 16);
}
__device__ __forceinline__ float bf2f(u16 h) {
    union { unsigned int u; float f; } v; v.u = (unsigned)h << 16;
    return v.f;
}
__device__ __forceinline__ void split2(float x, u16& hi, u16& lo) {
    const u16 h = f2bf(x);
    hi = h;
    lo = f2bf(x - bf2f(h));                                // residual ~2^-17 relative
}

// Swizzled LDS tile [64 rows][64 bf16] (128 B rows): byte ^= (row&7)<<4.
__device__ __forceinline__ s16x8 ldf(const u16* buf, int row, int chunk) {
    const int byte = (row * 128 + chunk * 16) ^ ((row & 7) << 4);
    return *(const s16x8*)((const char*)buf + byte);
}
__device__ __forceinline__ void st32(u16* buf, int row, int ch, s16x8 a, s16x8 b) {
    char* p = (char*)buf;
    *(s16x8*)(p + ((row * 128 + ch * 32) ^ ((row & 7) << 4)))      = a;
    *(s16x8*)(p + ((row * 128 + ch * 32 + 16) ^ ((row & 7) << 4))) = b;
}
// attn staging variant (round-4/6 validated): chunks ch and ch+4
__device__ __forceinline__ void st_stage(u16* buf, int t, s16x8 v0, s16x8 v1) {
    const int row = t >> 2, ch = t & 3;
    *(s16x8*)((char*)buf + ((row * 128 + ch * 16)       ^ ((row & 7) << 4))) = v0;
    *(s16x8*)((char*)buf + ((row * 128 + (ch + 4) * 16) ^ ((row & 7) << 4))) = v1;
}
__device__ __forceinline__ float hmax4(f32x4 v) {
    return fmaxf(fmaxf(v[0], v[1]), fmaxf(v[2], v[3]));
}
__device__ __forceinline__ float hsum4(f32x4 v) {
    return (v[0] + v[1]) + (v[2] + v[3]);
}

// ---------------------------------------------------------------------------
// Prep: split fp32 array into hi/lo bf16
// ---------------------------------------------------------------------------
__global__ __launch_bounds__(256)
void split_f32(const float* __restrict__ src, u16* __restrict__ hi,
               u16* __restrict__ lo, int n4)
{
    const int i = blockIdx.x * 256 + threadIdx.x;
    if (i >= n4) return;
    const float4 v = ((const float4*)src)[i];
    u16 h0,h1,h2,h3,l0,l1,l2,l3;
    split2(v.x,h0,l0); split2(v.y,h1,l1); split2(v.z,h2,l2); split2(v.w,h3,l3);
    u16x4 H = {h0,h1,h2,h3}, L = {l0,l1,l2,l3};
    ((u16x4*)hi)[i] = H;
    ((u16x4*)lo)[i] = L;
}

// ---------------------------------------------------------------------------
// Prep: transpose x [b][c][p] fp32 -> xT hi/lo [b][p][c] bf16 (64x64 tiles)
// ---------------------------------------------------------------------------
__global__ __launch_bounds__(256)
void xpose_x(const float* __restrict__ x, u16* __restrict__ xthi,
             u16* __restrict__ xtlo)
{
    __shared__ float T[64][68];
    const int t  = threadIdx.x;
    const int p0 = blockIdx.x * 64;
    const int c0 = blockIdx.y * 64;
    const int b  = blockIdx.z;
    const int cl = t >> 4, pj = (t & 15) * 4;
    #pragma unroll
    for (int k = 0; k < 4; ++k)
        *(float4*)&T[cl + 16 * k][pj] =
            *(const float4*)&x[((size_t)b * CIN + c0 + cl + 16 * k) * NTOK + p0 + pj];
    __syncthreads();
    const int p = t >> 2, ch = t & 3;
    u16* dhi = xthi + ((size_t)b * NTOK + p0 + p) * CIN + c0 + ch * 16;
    u16* dlo = xtlo + ((size_t)b * NTOK + p0 + p) * CIN + c0 + ch * 16;
    #pragma unroll
    for (int g = 0; g < 2; ++g) {
        s16x8 H, L;
        #pragma unroll
        for (int e = 0; e < 8; ++e) {
            u16 hh, ll;
            split2(T[ch * 16 + g * 8 + e][p], hh, ll);
            H[e] = (short)hh; L[e] = (short)ll;
        }
        *(s16x8*)(dhi + g * 8) = H;
        *(s16x8*)(dlo + g * 8) = L;
    }
}

// ---------------------------------------------------------------------------
// QKV projection, split-bf16 MFMA (round-6 validated, unchanged).
// ---------------------------------------------------------------------------
__global__ __launch_bounds__(256, 4)
void gemm_qkv_mfma(const u16* __restrict__ Whi, const u16* __restrict__ Wlo,
                   const u16* __restrict__ Xhi, const u16* __restrict__ Xlo,
                   u16* __restrict__ qkt, u16* __restrict__ vd)
{
    __shared__ __align__(16) char smem[32768];
    u16* Ah = (u16*)smem;
    u16* Al = (u16*)(smem + 8192);
    u16* Bh = (u16*)(smem + 16384);
    u16* Bl = (u16*)(smem + 24576);

    const int t = threadIdx.x;
    const int lane = t & 63, w = t >> 6;
    const int lr = lane & 15, lq = lane >> 4;
    const int p0 = blockIdx.x * 64;
    const int m0 = blockIdx.y * 64;
    const int b  = blockIdx.z;
    const int row = t >> 2, ch = t & 3;

    const u16* wh = Whi + (size_t)(m0 + row) * CIN + ch * 16;
    const u16* wl = Wlo + (size_t)(m0 + row) * CIN + ch * 16;
    const u16* xh = Xhi + ((size_t)b * NTOK + p0 + row) * CIN + ch * 16;
    const u16* xl = Xlo + ((size_t)b * NTOK + p0 + row) * CIN + ch * 16;

    f32x4 acc[4] = {};
    for (int kc = 0; kc < CIN; kc += 64) {
        __syncthreads();
        st32(Ah, row, ch, *(const s16x8*)(wh + kc), *(const s16x8*)(wh + kc + 8));
        st32(Al, row, ch, *(const s16x8*)(wl + kc), *(const s16x8*)(wl + kc + 8));
        st32(Bh, row, ch, *(const s16x8*)(xh + kc), *(const s16x8*)(xh + kc + 8));
        st32(Bl, row, ch, *(const s16x8*)(xl + kc), *(const s16x8*)(xl + kc + 8));
        __syncthreads();
        #pragma unroll
        for (int ks = 0; ks < 2; ++ks) {
            const s16x8 ah = ldf(Ah, w * 16 + lr, ks * 4 + lq);
            const s16x8 al = ldf(Al, w * 16 + lr, ks * 4 + lq);
            #pragma unroll
            for (int js = 0; js < 4; ++js) {
                const s16x8 bh = ldf(Bh, js * 16 + lr, ks * 4 + lq);
                const s16x8 bl = ldf(Bl, js * 16 + lr, ks * 4 + lq);
                acc[js] = __builtin_amdgcn_mfma_f32_16x16x32_bf16(ah, bh, acc[js], 0, 0, 0);
                acc[js] = __builtin_amdgcn_mfma_f32_16x16x32_bf16(al, bh, acc[js], 0, 0, 0);
                acc[js] = __builtin_amdgcn_mfma_f32_16x16x32_bf16(ah, bl, acc[js], 0, 0, 0);
            }
        }
    }

    __syncthreads();
    u16* T = Ah;
    char* Tc = (char*)T;
    if (m0 < 1024) {
        const float scale = (m0 < 512) ? ATT_SCALE : 1.0f;
        #pragma unroll
        for (int js = 0; js < 4; ++js) {
            const int p = js * 16 + lr;
            #pragma unroll
            for (int r = 0; r < 4; ++r) {
                const int o = w * 16 + lq * 4 + r;
                *(u16*)(Tc + ((p * 128 + o * 2) ^ ((p & 7) << 4))) = f2bf(acc[js][r] * scale);
            }
        }
        __syncthreads();
        const int sidx = (m0 < 512) ? 0 : 1;
        const int h = (m0 & 511) >> 6;
        u16* dst = qkt + ((((size_t)b * 2 + sidx) * NH + h) * NTOK + p0 + row) * 64 + ch * 16;
        *(s16x8*)dst       = *(const s16x8*)(Tc + ((row * 128 + ch * 32)      ^ ((row & 7) << 4)));
        *(s16x8*)(dst + 8) = *(const s16x8*)(Tc + ((row * 128 + ch * 32 + 16) ^ ((row & 7) << 4)));
    } else {
        const int h = (m0 - 1024) >> 6;
        #pragma unroll
        for (int js = 0; js < 4; ++js) {
            const int p = js * 16 + lr;
            #pragma unroll
            for (int r = 0; r < 4; ++r) {
                const int o = w * 16 + lq * 4 + r;
                *(u16*)(Tc + ((o * 128 + p * 2) ^ ((o & 7) << 4))) = f2bf(acc[js][r]);
            }
        }
        __syncthreads();
        u16* dst = vd + (((size_t)b * NH + h) * 64 + row) * NTOK + p0 + ch * 16;
        *(s16x8*)dst       = *(const s16x8*)(Tc + ((row * 128 + ch * 32)      ^ ((row & 7) << 4)));
        *(s16x8*)(dst + 8) = *(const s16x8*)(Tc + ((row * 128 + ch * 32 + 16) ^ ((row & 7) << 4)));
    }
}

// ---------------------------------------------------------------------------
// Flash attention, bf16 MFMA, SWAPPED QK^T softmax.
// S^T = mfma(A=K[j][d], B=Q[i][d]): lane owns query i = w*16+(lane&15) and
// 16 j-values j = js*16 + (lane>>4)*4 + r. Row-reduce = in-lane + shfl 16,32.
// m/l/corr are lane-local scalars (no LDS round-trip). P written as 4x u16x4.
// PV and output layout identical to round-6 validated code.
// ---------------------------------------------------------------------------
__global__ __launch_bounds__(256, 4)
void attn_kernel(const u16* __restrict__ qkt, const u16* __restrict__ vd,
                 float* __restrict__ attn_out)
{
    __shared__ __align__(16) u16 Qt[64 * 64];
    __shared__ __align__(16) u16 Kt[64 * 64];
    __shared__ __align__(16) u16 Vt[64 * 64];
    __shared__ __align__(16) u16 Ps[64 * 64];

    const int t    = threadIdx.x;
    const int lane = t & 63;
    const int w    = t >> 6;
    const int lr   = lane & 15;
    const int lq   = lane >> 4;

    const int bid     = blockIdx.x;
    const int logical = (bid & 7) * 128 + (bid >> 3);
    const int it = logical & 15;
    const int h  = (logical >> 4) & 7;
    const int b  = logical >> 7;
    const int i0 = it * 64;

    const int srow = t >> 2, sch = t & 3;
    const u16* qg = qkt + ((((size_t)b * 2 + 0) * NH + h) * NTOK + i0 + srow) * 64 + sch * 8;
    const u16* kg = qkt + ((((size_t)b * 2 + 1) * NH + h) * NTOK + srow) * 64 + sch * 8;
    const u16* vg = vd  + (((size_t)b * NH + h) * 64 + srow) * NTOK + sch * 8;

    st_stage(Qt, t, *(const s16x8*)qg, *(const s16x8*)(qg + 32));

    s16x8 k0 = *(const s16x8*)kg, k1 = *(const s16x8*)(kg + 32);
    s16x8 v0 = *(const s16x8*)vg, v1 = *(const s16x8*)(vg + 32);

    f32x4 o0 = {0.f,0.f,0.f,0.f}, o1 = o0, o2 = o0, o3 = o0;
    float m_run = -INFINITY, l_run = 0.0f;

    const int ii = w * 16 + lr;            // this lane's query row
    char* pr = (char*)Ps;

    for (int jt = 0; jt < 16; ++jt) {
        __syncthreads();
        st_stage(Kt, t, k0, k1);
        st_stage(Vt, t, v0, v1);
        const int jn = (jt + 1) & 15;
        k0 = *(const s16x8*)(kg + (size_t)jn * 4096);
        k1 = *(const s16x8*)(kg + (size_t)jn * 4096 + 32);
        v0 = *(const s16x8*)(vg + (size_t)jn * 64);
        v1 = *(const s16x8*)(vg + (size_t)jn * 64 + 32);
        __syncthreads();

        // ---- S^T tile: A = K rows j, B = Q rows i ----
        f32x4 s0 = {0.f,0.f,0.f,0.f}, s1 = s0, s2 = s0, s3 = s0;
        #pragma unroll
        for (int ks = 0; ks < 2; ++ks) {
            const s16x8 qb = ldf(Qt, w * 16 + lr, ks * 4 + lq);
            s0 = __builtin_amdgcn_mfma_f32_16x16x32_bf16(ldf(Kt,      lr, ks*4+lq), qb, s0, 0,0,0);
            s1 = __builtin_amdgcn_mfma_f32_16x16x32_bf16(ldf(Kt, 16 + lr, ks*4+lq), qb, s1, 0,0,0);
            s2 = __builtin_amdgcn_mfma_f32_16x16x32_bf16(ldf(Kt, 32 + lr, ks*4+lq), qb, s2, 0,0,0);
            s3 = __builtin_amdgcn_mfma_f32_16x16x32_bf16(ldf(Kt, 48 + lr, ks*4+lq), qb, s3, 0,0,0);
        }

        // ---- online softmax: lane-local row, reduce across lanes {i,i+16,i+32,i+48} ----
        float mt = fmaxf(fmaxf(hmax4(s0), hmax4(s1)), fmaxf(hmax4(s2), hmax4(s3)));
        mt = fmaxf(mt, __shfl_xor(mt, 16));
        mt = fmaxf(mt, __shfl_xor(mt, 32));
        const float mnew = fmaxf(m_run, mt);
        const float corr = __expf(m_run - mnew);
        f32x4 p0v, p1v, p2v, p3v;
        #pragma unroll
        for (int r = 0; r < 4; ++r) {
            p0v[r] = __expf(s0[r] - mnew);
            p1v[r] = __expf(s1[r] - mnew);
            p2v[r] = __expf(s2[r] - mnew);
            p3v[r] = __expf(s3[r] - mnew);
        }
        float lt = (hsum4(p0v) + hsum4(p1v)) + (hsum4(p2v) + hsum4(p3v));
        lt += __shfl_xor(lt, 16);
        lt += __shfl_xor(lt, 32);
        l_run = l_run * corr + lt;
        m_run = mnew;

        // ---- P writes: row ii, cols js*16+lq*4+{0..3}, packed 8B ----
        {
            u16x4 a = { f2bf(p0v[0]), f2bf(p0v[1]), f2bf(p0v[2]), f2bf(p0v[3]) };
            u16x4 bq= { f2bf(p1v[0]), f2bf(p1v[1]), f2bf(p1v[2]), f2bf(p1v[3]) };
            u16x4 c = { f2bf(p2v[0]), f2bf(p2v[1]), f2bf(p2v[2]), f2bf(p2v[3]) };
            u16x4 d = { f2bf(p3v[0]), f2bf(p3v[1]), f2bf(p3v[2]), f2bf(p3v[3]) };
            *(u16x4*)(pr + ((ii * 128 + ( 0 + lq * 4) * 2) ^ ((ii & 7) << 4))) = a;
            *(u16x4*)(pr + ((ii * 128 + (16 + lq * 4) * 2) ^ ((ii & 7) << 4))) = bq;
            *(u16x4*)(pr + ((ii * 128 + (32 + lq * 4) * 2) ^ ((ii & 7) << 4))) = c;
            *(u16x4*)(pr + ((ii * 128 + (48 + lq * 4) * 2) ^ ((ii & 7) << 4))) = d;
        }

        o0 *= corr; o1 *= corr; o2 *= corr; o3 *= corr;

        // ---- PV: O^T[d][i] += V[d][j] * P[i][j] (unchanged) ----
        #pragma unroll
        for (int ks = 0; ks < 2; ++ks) {
            const s16x8 pb = ldf(Ps, w * 16 + lr, ks * 4 + lq);
            o0 = __builtin_amdgcn_mfma_f32_16x16x32_bf16(ldf(Vt,      lr, ks*4+lq), pb, o0, 0,0,0);
            o1 = __builtin_amdgcn_mfma_f32_16x16x32_bf16(ldf(Vt, 16 + lr, ks*4+lq), pb, o1, 0,0,0);
            o2 = __builtin_amdgcn_mfma_f32_16x16x32_bf16(ldf(Vt, 32 + lr, ks*4+lq), pb, o2, 0,0,0);
            o3 = __builtin_amdgcn_mfma_f32_16x16x32_bf16(ldf(Vt, 48 + lr, ks*4+lq), pb, o3, 0,0,0);
        }
    }

    // ---- normalize (lane-local 1/l) and store O^T[d][i] fp32 (round-6 layout) ----
    const float inv = 1.0f / l_run;
    float* og = attn_out + (((size_t)b * NH + h) * 64) * NTOK + i0 + w * 16 + lr;
    #pragma unroll
    for (int r = 0; r < 4; ++r) {
        og[(size_t)( 0 + lq * 4 + r) * NTOK] = o0[r] * inv;
        og[(size_t)(16 + lq * 4 + r) * NTOK] = o1[r] * inv;
        og[(size_t)(32 + lq * 4 + r) * NTOK] = o2[r] * inv;
        og[(size_t)(48 + lq * 4 + r) * NTOK] = o3[r] * inv;
    }
}

// ---------------------------------------------------------------------------
// Output projection, split-bf16 MFMA (2 products), reading fp32 attn [b][o][tok].
// A = Wout[c][o] hi/lo; B staged by transpose-convert: Bt[tok][o] bf16.
// ---------------------------------------------------------------------------
__global__ __launch_bounds__(256, 4)
void gemm_out_mfma(const u16* __restrict__ Whi, const u16* __restrict__ Wlo,
                   const float* __restrict__ attn, const float* __restrict__ bias,
                   float* __restrict__ out)
{
    __shared__ __align__(16) char smem[24576];
    u16* Ah = (u16*)smem;
    u16* Al = (u16*)(smem + 8192);
    u16* Bt = (u16*)(smem + 16384);

    const int t = threadIdx.x;
    const int lane = t & 63, w = t >> 6;
    const int lr = lane & 15, lq = lane >> 4;
    const int p0 = blockIdx.x * 64;
    const int m0 = blockIdx.y * 64;
    const int b  = blockIdx.z;
    const int row = t >> 2, ch = t & 3;

    const u16* wh = Whi + (size_t)(m0 + row) * HIDDEN + ch * 16;
    const u16* wl = Wlo + (size_t)(m0 + row) * HIDDEN + ch * 16;
    const float* ab = attn + (size_t)b * HIDDEN * NTOK + p0;
    const int btok = t & 63;          // token row of Bt this thread stages
    const int bog  = (t >> 6) * 16;   // 16 o-columns per wave

    f32x4 acc[4] = {};
    for (int kc = 0; kc < HIDDEN; kc += 64) {
        __syncthreads();
        st32(Ah, row, ch, *(const s16x8*)(wh + kc), *(const s16x8*)(wh + kc + 8));
        st32(Al, row, ch, *(const s16x8*)(wl + kc), *(const s16x8*)(wl + kc + 8));
        // B: transpose-convert fp32 [o][tok] -> bf16 Bt[tok][o] (coalesced loads)
        {
            s16x8 H0, H1;
            #pragma unroll
            for (int e = 0; e < 8; ++e)
                H0[e] = (short)f2bf(ab[(size_t)(kc + bog + e) * NTOK + btok]);
            #pragma unroll
            for (int e = 0; e < 8; ++e)
                H1[e] = (short)f2bf(ab[(size_t)(kc + bog + 8 + e) * NTOK + btok]);
            char* bp = (char*)Bt;
            *(s16x8*)(bp + ((btok * 128 + bog * 2)      ^ ((btok & 7) << 4))) = H0;
            *(s16x8*)(bp + ((btok * 128 + bog * 2 + 16) ^ ((btok & 7) << 4))) = H1;
        }
        __syncthreads();
        #pragma unroll
        for (int ks = 0; ks < 2; ++ks) {
            const s16x8 ah = ldf(Ah, w * 16 + lr, ks * 4 + lq);
            const s16x8 al = ldf(Al, w * 16 + lr, ks * 4 + lq);
            #pragma unroll
            for (int js = 0; js < 4; ++js) {
                const s16x8 bh = ldf(Bt, js * 16 + lr, ks * 4 + lq);
                acc[js] = __builtin_amdgcn_mfma_f32_16x16x32_bf16(ah, bh, acc[js], 0, 0, 0);
                acc[js] = __builtin_amdgcn_mfma_f32_16x16x32_bf16(al, bh, acc[js], 0, 0, 0);
            }
        }
    }

    // epilogue: fp32 bounce T[c][p] (stride 68), bias, coalesced float4 stores
    __syncthreads();
    float* T = (float*)smem;              // 64*68*4 = 17408 B < 24576
    #pragma unroll
    for (int js = 0; js < 4; ++js) {
        const int p = js * 16 + lr;
        #pragma unroll
        for (int r = 0; r < 4; ++r)
            T[(w * 16 + lq * 4 + r) * 68 + p] = acc[js][r];
    }
    __syncthreads();
    const float bv = bias[m0 + row];
    float* dst = out + ((size_t)b * CIN + m0 + row) * NTOK + p0;
    #pragma unroll
    for (int q = 0; q < 4; ++q) {
        float4 v = *(const float4*)&T[row * 68 + ch * 4 + q * 16];
        v.x += bv; v.y += bv; v.z += bv; v.w += bv;
        *(float4*)&dst[ch * 4 + q * 16] = v;
    }
}

// ---------------------------------------------------------------------------
extern "C" void kernel_launch(void* const* d_in, const int* in_sizes, int n_in,
                              void* d_out, int out_size, void* d_ws, size_t ws_size,
                              hipStream_t stream)
{
    const float* x    = (const float*)d_in[0];   // [8][256][1024]
    const float* Wqkv = (const float*)d_in[1];   // [1536][256]
    const float* Wout = (const float*)d_in[2];   // [256][512]
    const float* bout = (const float*)d_in[3];   // [256]
    float* out = (float*)d_out;                  // [8][256][1024]

    char* ws = (char*)d_ws;
    u16* Wqhi = (u16*)ws;                         ws += (size_t)O3 * CIN * 2;
    u16* Wqlo = (u16*)ws;                         ws += (size_t)O3 * CIN * 2;
    u16* Wohi = (u16*)ws;                         ws += (size_t)CIN * HIDDEN * 2;
    u16* Wolo = (u16*)ws;                         ws += (size_t)CIN * HIDDEN * 2;
    u16* xThi = (u16*)ws;                         ws += (size_t)BATCH * NTOK * CIN * 2;
    u16* xTlo = (u16*)ws;                         ws += (size_t)BATCH * NTOK * CIN * 2;
    u16* qkt  = (u16*)ws;                         ws += (size_t)BATCH * 2 * NH * NTOK * HD * 2;
    u16* vd   = (u16*)ws;                         ws += (size_t)BATCH * NH * HD * NTOK * 2;
    float* attn = (float*)ws;                     ws += (size_t)BATCH * HIDDEN * NTOK * 4;

    split_f32<<<dim3(O3 * CIN / 1024), 256, 0, stream>>>(Wqkv, Wqhi, Wqlo, O3 * CIN / 4);
    split_f32<<<dim3(CIN * HIDDEN / 1024), 256, 0, stream>>>(Wout, Wohi, Wolo, CIN * HIDDEN / 4);
    xpose_x<<<dim3(16, 4, BATCH), 256, 0, stream>>>(x, xThi, xTlo);

    gemm_qkv_mfma<<<dim3(16, 24, BATCH), 256, 0, stream>>>(Wqhi, Wqlo, xThi, xTlo, qkt, vd);
    attn_kernel<<<dim3(1024), 256, 0, stream>>>(qkt, vd, attn);
    gemm_out_mfma<<<dim3(16, 4, BATCH), 256, 0, stream>>>(Wohi, Wolo, attn, bout, out);
}